// Round 5
// baseline (2253.134 us; speedup 1.0000x reference)
//
#include <hip/hip_runtime.h>

#define TT 4000   // timesteps
#define HH 64     // hidden
#define NB 256    // batch
#define EE 128    // fc out

typedef __attribute__((ext_vector_type(2))) _Float16 h2;
typedef __attribute__((ext_vector_type(8))) _Float16 h8;
typedef __attribute__((ext_vector_type(4))) int i4;

__device__ __forceinline__ float ftanh(float x) {
    return fmaf(2.f, __builtin_amdgcn_rcpf(1.f + __expf(-2.f * x)), -1.f);
}

#if __has_builtin(__builtin_amdgcn_fdot2)
#define FDOT2(a, b, c) __builtin_amdgcn_fdot2((a), (b), (c), false)
#else
#define FDOT2(a, b, c) fmaf((float)(a).x, (float)(b).x, fmaf((float)(a).y, (float)(b).y, (c)))
#endif

// h2 sub-extract from h8 register (sub-register addressing, no memory).
#define H2V(V, i) (__builtin_shufflevector((V), (V), 2 * (i), 2 * (i) + 1))

// DPP helpers (VALU pipe, no LDS). ctrl must be an ICE -> template param.
template <int CTRL>
__device__ __forceinline__ float dpp_mov(float v) {
    return __int_as_float(__builtin_amdgcn_update_dpp(
        0, __float_as_int(v), CTRL, 0xF, 0xF, true));
}
// Dword-wise DPP over an h8 (4 VGPRs).
template <int CTRL>
__device__ __forceinline__ h8 dpp_h8(h8 v) {
    i4 a = __builtin_bit_cast(i4, v), r;
    r.x = __builtin_amdgcn_update_dpp(0, a.x, CTRL, 0xF, 0xF, true);
    r.y = __builtin_amdgcn_update_dpp(0, a.y, CTRL, 0xF, 0xF, true);
    r.z = __builtin_amdgcn_update_dpp(0, a.z, CTRL, 0xF, 0xF, true);
    r.w = __builtin_amdgcn_update_dpp(0, a.w, CTRL, 0xF, 0xF, true);
    return __builtin_bit_cast(h8, r);
}
#define DPP_XOR1 0xB1   // quad_perm [1,0,3,2]  (flip s)      [HW-verified R8/R9]
#define DPP_XOR2 0x4E   // quad_perm [2,3,0,1]  (flip u)      [HW-verified R8/R9]
#define DPP_FB   0x44   // quad_perm [0,1,0,1]  (sel uu=0 partner, per s)
#define DPP_OB   0xEE   // quad_perm [2,3,2,3]  (sel uu=1 partner, per s)
#define DPP_SHR4 0x114  // row_shr:4            (p=0 quad -> p=1 quad) [R13-verified]

#define CVT2(d0, d1, s) h2 d0 = h2{(_Float16)(s).x, (_Float16)(s).y}, \
                           d1 = h2{(_Float16)(s).z, (_Float16)(s).w};

// R18: TLP + lean DS. Evidence chain: R14 (-32 b128/CU) = -92cyc; R15 (+32
// dpp) = +63cyc == issue cost; R17 (explicit interleave) = null (compiler
// already schedules). Per-SIMD VALU issue is only ~300-400cyc of the
// 1131-cyc step; VALUBusy=63% is a 4-SIMD union (~30%/SIMD) -> ~600cyc of
// UNHIDDEN latency (LDS round-trip, trans tails, dot latency) with 1
// wave/SIMD. Fix: back to 512thr/8 waves (2/SIMD -> wave A's issue fills
// wave B's stalls) — but R13's DS bottleneck (64 b128/CU ~= 768cyc) is
// avoided with the R15 quad-cooperative read (4 b128/lane + DPP rebuild,
// correctness-verified in R15): DS stays at 32 b128/CU (~384cyc). Per-lane
// work halves vs R14 (1 n/lane, 48 fdot2) -> shorter per-wave critical path.
//
// lane = 16*rowgrp + 8*nn + 4*p + 2*u + s ; n = w*8 + rowgrp*2 + nn (0..63);
// gate = p + 2u (p=0 quad: i,i,g,g ; p=1 quad: f,f,o,o), s = k-half AND
// layer assignment.
//
// Quad-cooperative read: lane (ss,uu) reads its 64B quarter (4 b128:
// uu=0 -> h0-slice, uu=1 -> h1-slice, per ss); quad_perm 0x44/0xEE rebuild
// canonical H (h0) and G (h1) slices in all lanes [HW-verified R15].
//
// Layer pipelining (verified R3-R10): iter t computes L0 gates(t) from
// h0(t-1) and L1 gates(t-1) from {h1(t-2), h0(t-1)}; s=0 lanes run the L0
// act/cell path, s=1 the L1 path. 1 barrier/step, h fp16 double-buffered.
__global__ __launch_bounds__(512, 2)
void lstm2_fc_kernel(const float* __restrict__ x,      // [B, T, 1]
                     const float* __restrict__ W_ih0,  // [256, 1]
                     const float* __restrict__ W_hh0,  // [256, 64]
                     const float* __restrict__ b_ih0,  // [256]
                     const float* __restrict__ b_hh0,  // [256]
                     const float* __restrict__ W_ih1,  // [256, 64]
                     const float* __restrict__ W_hh1,  // [256, 64]
                     const float* __restrict__ b_ih1,  // [256]
                     const float* __restrict__ b_hh1,  // [256]
                     const float* __restrict__ W_fc,   // [128, 64]
                     const float* __restrict__ b_fc,   // [128]
                     float* __restrict__ out)          // [B, 128]
{
    const int b    = blockIdx.x;
    const int tid  = threadIdx.x;     // 0..511
    const int w    = tid >> 6;        // wave 0..7
    const int lane = tid & 63;
    const int ss   = lane & 1;        // k-half AND layer assignment
    const int uu   = (lane >> 1) & 1;
    const int pp   = (lane >> 2) & 1;
    const int nn   = (lane >> 3) & 1;
    const int n    = w * 8 + (lane >> 4) * 2 + nn;   // h-index 0..63
    const int gidx = pp + 2 * uu;                    // 0:i 1:f 2:g 3:o

    __shared__ float x_s[TT];                          // 16 KB
    __shared__ __align__(16) _Float16 hbuf[2][2 * HH]; // [parity][h0|h1], fp16

    for (int t = tid; t < TT; t += 512) x_s[t] = x[(size_t)b * TT + t];
    if (tid < 4 * HH) ((_Float16*)hbuf)[tid] = (_Float16)0.f;

    const int row = gidx * HH + n;   // gate row in [0,256)
    // --- Named-scalar weight load: 3 thirty-two-wide slices -> 48 h2 ---
    const float4* p0 = (const float4*)(W_hh0 + row * HH + ss * 32);
    const float4* p1 = (const float4*)(W_ih1 + row * HH + ss * 32);
    const float4* p2 = (const float4*)(W_hh1 + row * HH + ss * 32);
    float4 qa0 = p0[0], qa1 = p0[1], qa2 = p0[2], qa3 = p0[3];
    float4 qa4 = p0[4], qa5 = p0[5], qa6 = p0[6], qa7 = p0[7];
    float4 qb0 = p1[0], qb1 = p1[1], qb2 = p1[2], qb3 = p1[3];
    float4 qb4 = p1[4], qb5 = p1[5], qb6 = p1[6], qb7 = p1[7];
    float4 qc0 = p2[0], qc1 = p2[1], qc2 = p2[2], qc3 = p2[3];
    float4 qc4 = p2[4], qc5 = p2[5], qc6 = p2[6], qc7 = p2[7];
    CVT2(A0,  A1,  qa0) CVT2(A2,  A3,  qa1) CVT2(A4,  A5,  qa2) CVT2(A6,  A7,  qa3)
    CVT2(A8,  A9,  qa4) CVT2(A10, A11, qa5) CVT2(A12, A13, qa6) CVT2(A14, A15, qa7)
    CVT2(B0,  B1,  qb0) CVT2(B2,  B3,  qb1) CVT2(B4,  B5,  qb2) CVT2(B6,  B7,  qb3)
    CVT2(B8,  B9,  qb4) CVT2(B10, B11, qb5) CVT2(B12, B13, qb6) CVT2(B14, B15, qb7)
    CVT2(C0,  C1,  qc0) CVT2(C2,  C3,  qc1) CVT2(C4,  C5,  qc2) CVT2(C6,  C7,  qc3)
    CVT2(C8,  C9,  qc4) CVT2(C10, C11, qc5) CVT2(C12, C13, qc6) CVT2(C14, C15, qc7)

    float wx  = W_ih0[row];
    float bb0 = b_ih0[row] + b_hh0[row];
    float bb1 = b_ih1[row] + b_hh1[row];

    // Remat fences (R7/R9-proven).
    asm volatile("" : "+v"(A0), "+v"(A1), "+v"(A2),  "+v"(A3),
                      "+v"(A4), "+v"(A5), "+v"(A6),  "+v"(A7),
                      "+v"(A8), "+v"(A9), "+v"(A10), "+v"(A11),
                      "+v"(A12),"+v"(A13),"+v"(A14), "+v"(A15),
                      "+v"(B0), "+v"(B1), "+v"(B2),  "+v"(B3),
                      "+v"(B4), "+v"(B5), "+v"(B6),  "+v"(B7));
    asm volatile("" : "+v"(B8), "+v"(B9), "+v"(B10), "+v"(B11),
                      "+v"(B12),"+v"(B13),"+v"(B14), "+v"(B15),
                      "+v"(C0), "+v"(C1), "+v"(C2),  "+v"(C3),
                      "+v"(C4), "+v"(C5), "+v"(C6),  "+v"(C7),
                      "+v"(C8), "+v"(C9), "+v"(C10), "+v"(C11),
                      "+v"(C12),"+v"(C13),"+v"(C14), "+v"(C15),
                      "+v"(wx), "+v"(bb0),"+v"(bb1));

    // act(z) = mm * rcp(1 + exp(kk*z)) + aa ; tanh only for gate g (gidx==2).
    const bool isg = (gidx == 2);
    const float kk = isg ? -2.f : -1.f;
    const float mm = isg ?  2.f :  1.f;
    const float aa = isg ? -1.f :  0.f;

    const bool wlane = (pp == 1) && (uu == 0);   // h writers (f lanes)
    const int  hoff  = ss * HH + n;              // s=0 -> h0[n], s=1 -> h1[n]
    const int  rdofs = 4 * ss + 8 * uu;          // this lane's h8 read quarter
    float cc = 0.f;                              // valid in p=1 lanes

    __syncthreads();

    // One fdot2 from each of the 3 chains per row (compiler may reorder;
    // R17 showed it schedules well either way).
    #define ROW(Aj, Bj, Cj, Hv, Gv, e) \
        s0 = FDOT2(Aj, H2V(Hv, e), s0); \
        s1 = FDOT2(Bj, H2V(Hv, e), s1); \
        s2 = FDOT2(Cj, H2V(Gv, e), s2);

    for (int t = 0; t <= TT; ++t) {
        const float xt = x_s[(t < TT) ? t : 0];
        const h8* hb = (const h8*)hbuf[t & 1];
        // Quad-cooperative read: 4 x b128 = this lane's (ss,uu) quarter.
        h8 R0 = hb[rdofs + 0], R1 = hb[rdofs + 1];
        h8 R2 = hb[rdofs + 2], R3 = hb[rdofs + 3];

        // 3 chains, 16 links each.
        float s0 = ss ? 0.f : fmaf(xt, wx, bb0);   // A: L0
        float s1 = ss ? 0.f : bb1;                 // B: L1 h0-part
        float s2 = 0.f;                            // C: L1 h1-part

        // Rebuild canonical slices just before use (staggers lgkm waits):
        // H (h0 k-slice) from uu=0 lanes, G (h1 k-slice) from uu=1 lanes.
        h8 Ha = dpp_h8<DPP_FB>(R0), Ga = dpp_h8<DPP_OB>(R0);
        ROW(A0,  B0,  C0,  Ha, Ga, 0)
        ROW(A1,  B1,  C1,  Ha, Ga, 1)
        ROW(A2,  B2,  C2,  Ha, Ga, 2)
        ROW(A3,  B3,  C3,  Ha, Ga, 3)
        h8 Hc = dpp_h8<DPP_FB>(R1), Gc = dpp_h8<DPP_OB>(R1);
        ROW(A4,  B4,  C4,  Hc, Gc, 0)
        ROW(A5,  B5,  C5,  Hc, Gc, 1)
        ROW(A6,  B6,  C6,  Hc, Gc, 2)
        ROW(A7,  B7,  C7,  Hc, Gc, 3)
        h8 He = dpp_h8<DPP_FB>(R2), Ge = dpp_h8<DPP_OB>(R2);
        ROW(A8,  B8,  C8,  He, Ge, 0)
        ROW(A9,  B9,  C9,  He, Ge, 1)
        ROW(A10, B10, C10, He, Ge, 2)
        ROW(A11, B11, C11, He, Ge, 3)
        h8 Hg = dpp_h8<DPP_FB>(R3), Gg = dpp_h8<DPP_OB>(R3);
        ROW(A12, B12, C12, Hg, Gg, 0)
        ROW(A13, B13, C13, Hg, Gg, 1)
        ROW(A14, B14, C14, Hg, Gg, 2)
        ROW(A15, B15, C15, Hg, Gg, 3)

        float acc0 = s0;
        float acc1 = s1 + s2;

        // s-butterfly (DPP xor1): both s-lanes hold full row sums.
        acc0 += dpp_mov<DPP_XOR1>(acc0);
        acc1 += dpp_mov<DPP_XOR1>(acc1);

        // Per-lane layer: s=0 -> L0(t), s=1 -> L1(t-1). One activation each.
        float z  = ss ? acc1 : acc0;
        float ez = __expf(kk * z);
        float val = fmaf(mm, __builtin_amdgcn_rcpf(1.f + ez), aa);

        // Gate combine, all DPP:
        //  p=0 quad (i,i,g,g): ig = val * xor2(val)     [per s]
        //  row_shr:4 hands ig to the p=1 quad (f,f,o,o) [dest i <- src i-4]
        //  f/o broadcast per s via quad_perm 0x44/0xEE
        float igq = val * dpp_mov<DPP_XOR2>(val);
        float ig  = dpp_mov<DPP_SHR4>(igq);
        float fb  = dpp_mov<DPP_FB>(val);
        float ob  = dpp_mov<DPP_OB>(val);

        float cn = fmaf(fb, cc, ig);
        float hn = ob * ftanh(cn);
        bool ok = ss ? (t > 0) : (t < TT);       // L1 skip at 0, L0 at TT
        cc = ok ? cn : cc;
        if (wlane && ok) hbuf[(t + 1) & 1][hoff] = (_Float16)hn;

        __syncthreads();                         // h exchange (double-buffered)
    }
    #undef ROW

    // FC on final h1 = h1(TT-1), in hbuf[(TT+1)&1][64..128).
    if (tid < EE) {
        const _Float16* h1f = &hbuf[(TT + 1) & 1][HH];
        float acc = b_fc[tid];
        const float4* wf = (const float4*)(W_fc + tid * HH);
        #pragma unroll
        for (int k = 0; k < HH / 4; ++k) {
            float4 v = wf[k];
            acc = fmaf(v.x, (float)h1f[4*k+0], acc);
            acc = fmaf(v.y, (float)h1f[4*k+1], acc);
            acc = fmaf(v.z, (float)h1f[4*k+2], acc);
            acc = fmaf(v.w, (float)h1f[4*k+3], acc);
        }
        out[(size_t)b * EE + tid] = acc;
    }
}

extern "C" void kernel_launch(void* const* d_in, const int* in_sizes, int n_in,
                              void* d_out, int out_size, void* d_ws, size_t ws_size,
                              hipStream_t stream) {
    const float* x     = (const float*)d_in[0];
    const float* W_ih0 = (const float*)d_in[1];
    const float* W_hh0 = (const float*)d_in[2];
    const float* b_ih0 = (const float*)d_in[3];
    const float* b_hh0 = (const float*)d_in[4];
    const float* W_ih1 = (const float*)d_in[5];
    const float* W_hh1 = (const float*)d_in[6];
    const float* b_ih1 = (const float*)d_in[7];
    const float* b_hh1 = (const float*)d_in[8];
    const float* W_fc  = (const float*)d_in[9];
    const float* b_fc  = (const float*)d_in[10];
    float* out = (float*)d_out;

    lstm2_fc_kernel<<<dim3(NB), dim3(512), 0, stream>>>(
        x, W_ih0, W_hh0, b_ih0, b_hh0, W_ih1, W_hh1, b_ih1, b_hh1, W_fc, b_fc, out);
}